// Round 10
// baseline (921.352 us; speedup 1.0000x reference)
//
#include <hip/hip_runtime.h>
#include <math.h>

typedef _Float16 f16;
typedef f16 f16x2 __attribute__((ext_vector_type(2)));
typedef f16 f16x8 __attribute__((ext_vector_type(8)));
typedef float f32x4 __attribute__((ext_vector_type(4)));

template <int V> struct VecT;
template <> struct VecT<2> { using T = f16 __attribute__((ext_vector_type(2))); };
template <> struct VecT<8> { using T = f16 __attribute__((ext_vector_type(8))); };

__device__ __forceinline__ unsigned ordf(float f) {
  unsigned u = __float_as_uint(f);
  return (u >> 31) ? ~u : (u | 0x80000000u);
}
__device__ __forceinline__ float unordf(unsigned u) {
  return (u >> 31) ? __uint_as_float(u & 0x7fffffffu) : __uint_as_float(~u);
}

__device__ __forceinline__ f16x8 cvt8(float4 a, float4 b) {
  f16x8 r;
  r[0] = (f16)a.x; r[1] = (f16)a.y; r[2] = (f16)a.z; r[3] = (f16)a.w;
  r[4] = (f16)b.x; r[5] = (f16)b.y; r[6] = (f16)b.z; r[7] = (f16)b.w;
  return r;
}

// ---------------------------------------------------------------------------
// Software grid barrier (persistent kernel, all blocks co-resident).
// Monotone arrival counter, device-scope atomics; fences give release/acquire
// so cross-XCD data written via atomics before the barrier is visible after.
// ---------------------------------------------------------------------------
__device__ __forceinline__ void gridbar(int* arrive, int ph) {
  __syncthreads();
  if (threadIdx.x == 0) {
    __threadfence();                       // release prior writes
    atomicAdd(arrive, 1);
    int target = ph * (int)gridDim.x;
    while (atomicAdd(arrive, 0) < target) __builtin_amdgcn_s_sleep(2);
    __threadfence();                       // acquire
  }
  __syncthreads();
}

// ---------------------------------------------------------------------------
// Fused CSR build: histogram -> hierarchical scan -> cursor init -> fill,
// one persistent kernel (256 blocks x 256 thr), 4 grid barriers.
// All cross-phase scalars move through device-scope atomics (XCD-safe).
// Edge id space: [0, E) = real edges, [E, E+N) = self loops (src=dst=id-E)
// ---------------------------------------------------------------------------
__global__ __launch_bounds__(256) void k_csr(
    const int* __restrict__ dstArr, int* cnt, int* row_ptr, int* cursor,
    int* __restrict__ perm, int* bsum, int* arrive,
    int n, int E, int Et, int nch) {
  __shared__ int part[256];
  int t = threadIdx.x;
  int b = blockIdx.x;
  int gid = b * 256 + t;
  int gsz = gridDim.x * 256;

  // phase 1: histogram of dst
  for (int i = gid; i < Et; i += gsz) {
    int d = (i < E) ? dstArr[i] : (i - E);
    atomicAdd(&cnt[d], 1);
  }
  gridbar(arrive, 1);

  // phase 2: per-1024-chunk local scan (blocks 0..nch-1)
  if (b < nch) {
    int base = b * 1024 + t * 4;
    int v0 = 0, v1 = 0, v2 = 0, v3 = 0;
    if (base + 0 < n) v0 = atomicAdd(&cnt[base + 0], 0);
    if (base + 1 < n) v1 = atomicAdd(&cnt[base + 1], 0);
    if (base + 2 < n) v2 = atomicAdd(&cnt[base + 2], 0);
    if (base + 3 < n) v3 = atomicAdd(&cnt[base + 3], 0);
    part[t] = v0 + v1 + v2 + v3;
    __syncthreads();
    for (int off = 1; off < 256; off <<= 1) {
      int x = (t >= off) ? part[t - off] : 0;
      __syncthreads();
      part[t] += x;
      __syncthreads();
    }
    int p0 = (t == 0) ? 0 : part[t - 1];
    if (base + 0 < n) atomicExch(&row_ptr[base + 0], p0);
    if (base + 1 < n) atomicExch(&row_ptr[base + 1], p0 + v0);
    if (base + 2 < n) atomicExch(&row_ptr[base + 2], p0 + v0 + v1);
    if (base + 3 < n) atomicExch(&row_ptr[base + 3], p0 + v0 + v1 + v2);
    if (t == 255) atomicExch(&bsum[b], part[255]);
  }
  gridbar(arrive, 2);

  // phase 3: scan chunk totals (block 0; nch <= 256)
  if (b == 0) {
    int v = (t < nch) ? atomicAdd(&bsum[t], 0) : 0;
    part[t] = v;
    __syncthreads();
    for (int off = 1; off < 256; off <<= 1) {
      int x = (t >= off) ? part[t - off] : 0;
      __syncthreads();
      part[t] += x;
      __syncthreads();
    }
    if (t < nch) atomicExch(&bsum[t], (t == 0) ? 0 : part[t - 1]);
    if (t == 255) atomicExch(&bsum[nch], part[255]);
  }
  gridbar(arrive, 3);

  // phase 4: add chunk offsets, init cursor
  for (int i = gid; i < n; i += gsz) {
    int bs = atomicAdd(&bsum[i >> 10], 0);
    int old = atomicAdd(&row_ptr[i], bs);
    atomicExch(&cursor[i], old + bs);
  }
  if (gid == 0) atomicExch(&row_ptr[n], atomicAdd(&bsum[nch], 0));
  gridbar(arrive, 4);

  // phase 5: fill permutation
  for (int i = gid; i < Et; i += gsz) {
    int d = (i < E) ? dstArr[i] : (i - E);
    int pos = atomicAdd(&cursor[d], 1);
    perm[pos] = i;  // plain store: consumed by later kernels only
  }
}

// ---------------------------------------------------------------------------
// fp32 -> fp16 conversion, 3 weight segments in one launch
// ---------------------------------------------------------------------------
__global__ void k_f2h3(const float* s0, f16* d0, int n0,
                       const float* s1, f16* d1, int n1,
                       const float* s2, f16* d2, int n2) {
  int i = blockIdx.x * blockDim.x + threadIdx.x;
  const float* s; f16* d;
  if (i < n0) { s = s0; d = d0; }
  else if ((i -= n0) < n1) { s = s1; d = d1; }
  else if ((i -= n1) < n2) { s = s2; d = d2; }
  else return;
  float4 v = ((const float4*)s)[i];
  union { f16 h[4]; double dd; } u;
  u.h[0] = (f16)v.x; u.h[1] = (f16)v.y; u.h[2] = (f16)v.z; u.h[3] = (f16)v.w;
  ((double*)d)[i] = u.dd;
}

// ---------------------------------------------------------------------------
// HGEMM (fp16 MFMA, fp32 accumulate): C[M,Nn] = A[M,K] @ B[Nn,K]^T
// 128x128 tile, BK=32, 256 thr = 4 waves, wave = 64x64 quadrant (4x4 MFMAs).
// B staged via global_load_lds width=16; A either the same (AF32=false) or
// fp32 source converted in-flight (AF32=true: float4 loads -> cvt ->
// ds_write_b128, same xor chunk swizzle chunk_lds = chunk_glob ^ ((row>>1)&3)).
// Fused GAT-attention epilogue (block covers one head's 128 cols).
// ---------------------------------------------------------------------------
template <bool AF32>
__global__ __launch_bounds__(256) void k_hgemm_nt(
    const void* __restrict__ Ain, const f16* __restrict__ B,
    f16* __restrict__ C, int M, int Nn, int K,
    const float* __restrict__ a_src, const float* __restrict__ a_dst,
    float* __restrict__ sArr, float* __restrict__ dArr,
    unsigned* __restrict__ gmaxU, int H) {
  __shared__ f16 As[128 * 32];
  __shared__ f16 Bs[128 * 32];
  int tid = threadIdx.x;
  int wave = tid >> 6, lane = tid & 63;
  int quad = lane >> 4, l16 = lane & 15;
  int m0 = blockIdx.y * 128, n0 = blockIdx.x * 128;
  int wm = (wave & 1) * 64, wn = (wave >> 1) * 64;

  // staging geometry (wave w stages rows w*16.. and 64+w*16..)
  int lr = lane >> 2;                // row within 16-row group
  int lc = lane & 3;                 // lds chunk slot this lane fills
  int chunk = lc ^ ((lr >> 1) & 3);  // global chunk to fetch (swizzle)
  int rb0 = wave * 16;
  int rb1 = 64 + wave * 16;
  int ga0 = m0 + rb0 + lr; if (ga0 >= M) ga0 = M - 1;
  int ga1 = m0 + rb1 + lr; if (ga1 >= M) ga1 = M - 1;

  const f16* gA0 = nullptr; const f16* gA1 = nullptr;
  const float* gA0f = nullptr; const float* gA1f = nullptr;
  if constexpr (AF32) {
    const float* Af = (const float*)Ain;
    gA0f = Af + (size_t)ga0 * K + chunk * 8;
    gA1f = Af + (size_t)ga1 * K + chunk * 8;
  } else {
    const f16* Ah = (const f16*)Ain;
    gA0 = Ah + (size_t)ga0 * K + chunk * 8;
    gA1 = Ah + (size_t)ga1 * K + chunk * 8;
  }
  const f16* gB0 = B + (size_t)(n0 + rb0 + lr) * K + chunk * 8;
  const f16* gB1 = B + (size_t)(n0 + rb1 + lr) * K + chunk * 8;
  f16* lA0 = &As[rb0 * 32];                       // wave-uniform base (lds path)
  f16* lA1 = &As[rb1 * 32];
  f16* lB0 = &Bs[rb0 * 32];
  f16* lB1 = &Bs[rb1 * 32];
  f16* lwA0 = &As[(rb0 + lr) * 32 + lc * 8];      // per-lane addr (ds_write path)
  f16* lwA1 = &As[(rb1 + lr) * 32 + lc * 8];

  // fragment read pointers (lds chunk = quad ^ ((l16>>1)&3) holds glob chunk quad)
  int rsw = (quad ^ ((l16 >> 1) & 3)) * 8;
  const f16* Ard[4];
  const f16* Brd[4];
#pragma unroll
  for (int i = 0; i < 4; ++i) {
    Ard[i] = &As[(wm + i * 16 + l16) * 32 + rsw];
    Brd[i] = &Bs[(wn + i * 16 + l16) * 32 + rsw];
  }

  f32x4 acc[4][4];
#pragma unroll
  for (int i = 0; i < 4; ++i)
#pragma unroll
    for (int j = 0; j < 4; ++j) acc[i][j] = (f32x4)(0.f);

  for (int k0 = 0; k0 < K; k0 += 32) {
    f16x8 wa0, wa1;
    if constexpr (AF32) {
      float4 u00 = *(const float4*)(gA0f + k0);
      float4 u01 = *(const float4*)(gA0f + k0 + 4);
      float4 u10 = *(const float4*)(gA1f + k0);
      float4 u11 = *(const float4*)(gA1f + k0 + 4);
      wa0 = cvt8(u00, u01);
      wa1 = cvt8(u10, u11);
    }
    __syncthreads();  // previous iteration's LDS reads complete
    if constexpr (AF32) {
      *(f16x8*)lwA0 = wa0;
      *(f16x8*)lwA1 = wa1;
    } else {
      __builtin_amdgcn_global_load_lds(
          (const __attribute__((address_space(1))) void*)(gA0 + k0),
          (__attribute__((address_space(3))) void*)lA0, 16, 0, 0);
      __builtin_amdgcn_global_load_lds(
          (const __attribute__((address_space(1))) void*)(gA1 + k0),
          (__attribute__((address_space(3))) void*)lA1, 16, 0, 0);
    }
    __builtin_amdgcn_global_load_lds(
        (const __attribute__((address_space(1))) void*)(gB0 + k0),
        (__attribute__((address_space(3))) void*)lB0, 16, 0, 0);
    __builtin_amdgcn_global_load_lds(
        (const __attribute__((address_space(1))) void*)(gB1 + k0),
        (__attribute__((address_space(3))) void*)lB1, 16, 0, 0);
    __syncthreads();  // drains vmcnt+lgkmcnt -> staged tile visible
    f16x8 af[4], bf[4];
#pragma unroll
    for (int i = 0; i < 4; ++i) af[i] = *(const f16x8*)Ard[i];
#pragma unroll
    for (int j = 0; j < 4; ++j) bf[j] = *(const f16x8*)Brd[j];
#pragma unroll
    for (int i = 0; i < 4; ++i)
#pragma unroll
      for (int j = 0; j < 4; ++j)
        acc[i][j] = __builtin_amdgcn_mfma_f32_16x16x32_f16(af[i], bf[j], acc[i][j], 0, 0, 0);
  }

  // ---- C store ----
#pragma unroll
  for (int i = 0; i < 4; ++i) {
#pragma unroll
    for (int r = 0; r < 4; ++r) {
      int m = m0 + wm + i * 16 + quad * 4 + r;
      if (m < M) {
        f16* Cp = C + (size_t)m * Nn + n0 + wn + l16;
#pragma unroll
        for (int j = 0; j < 4; ++j) Cp[j * 16] = (f16)acc[i][j][r];
      }
    }
  }

  // ---- fused attention scalars ----
  float av[4], ad[4];
#pragma unroll
  for (int j = 0; j < 4; ++j) {
    int col = n0 + wn + l16 + j * 16;
    av[j] = a_src[col];
    ad[j] = a_dst[col];
  }
  float sp[16], dp[16];
#pragma unroll
  for (int i = 0; i < 4; ++i)
#pragma unroll
    for (int r = 0; r < 4; ++r) {
      float ss = 0.f, dd = 0.f;
#pragma unroll
      for (int j = 0; j < 4; ++j) {
        ss += acc[i][j][r] * av[j];
        dd += acc[i][j][r] * ad[j];
      }
#pragma unroll
      for (int msk = 1; msk < 16; msk <<= 1) {
        ss += __shfl_xor(ss, msk);
        dd += __shfl_xor(dd, msk);
      }
      sp[i * 4 + r] = ss;
      dp[i * 4 + r] = dd;
    }

  __syncthreads();  // done reading As/Bs; reuse as float scratch
  float* fb = (float*)As;
  int wv = wn >> 6;
  if (l16 == 0) {
#pragma unroll
    for (int i = 0; i < 4; ++i)
#pragma unroll
      for (int r = 0; r < 4; ++r) {
        int row = wm + i * 16 + quad * 4 + r;
        fb[wv * 128 + row] = sp[i * 4 + r];
        fb[256 + wv * 128 + row] = dp[i * 4 + r];
      }
  }
  __syncthreads();
  if (tid < 128) {
    int m = m0 + tid;
    if (m < M) {
      float s = fb[tid] + fb[128 + tid];
      float d = fb[256 + tid] + fb[384 + tid];
      int head = n0 >> 7;
      sArr[(size_t)m * H + head] = s;
      dArr[(size_t)m * H + head] = d;
      atomicMax(&gmaxU[head], ordf(s));
    }
  }
}

// ---------------------------------------------------------------------------
// Segment softmax + aggregation: ONE WAVE PER NODE, no barriers, no LDS.
// Shift = leaky(gmax + d_n) >= segment max (leaky monotone; softmax
// shift-invariant). gmax passed as order-preserving uint.
// ---------------------------------------------------------------------------
template <int HH, int CT, bool DOELU, typename OutT>
__global__ __launch_bounds__(256) void k_aggregate(
    const f16* __restrict__ hin, const float* __restrict__ sArr,
    const float* __restrict__ dArr, const int* __restrict__ row_ptr,
    const int* __restrict__ perm, const int* __restrict__ srcArr,
    const unsigned* __restrict__ gmaxU, const float* __restrict__ bias,
    OutT* __restrict__ outp, int N, int E) {
  constexpr int VEC = CT / 64;
  constexpr int CPER = CT / HH;
  using gvec = typename VecT<VEC>::T;

  int n = blockIdx.x * 4 + (threadIdx.x >> 6);
  int lane = threadIdx.x & 63;
  if (n >= N) return;
  int e0 = row_ptr[n];
  int deg = row_ptr[n + 1] - e0;

  float dloc[HH], mn[HH];
#pragma unroll
  for (int h = 0; h < HH; ++h) {
    dloc[h] = dArr[n * HH + h];
    float m = unordf(gmaxU[h]) + dloc[h];
    mn[h] = (m > 0.f) ? m : 0.2f * m;
  }

  const int lanehead = (HH == 1) ? 0 : (lane * VEC) / CPER;
  float acc[VEC];
#pragma unroll
  for (int k = 0; k < VEC; ++k) acc[k] = 0.f;
  float denom[HH];
#pragma unroll
  for (int h = 0; h < HH; ++h) denom[h] = 0.f;

  for (int base = 0; base < deg; base += 64) {
    int cn = min(64, deg - base);
    int s_l = n;
    float w_l[HH];
#pragma unroll
    for (int h = 0; h < HH; ++h) w_l[h] = 0.f;
    if (lane < cn) {
      int eid = perm[e0 + base + lane];
      s_l = (eid < E) ? srcArr[eid] : (eid - E);
      if (HH == 4) {
        float4 sv = ((const float4*)sArr)[s_l];
        float svv[4] = {sv.x, sv.y, sv.z, sv.w};
#pragma unroll
        for (int h = 0; h < 4; ++h) {
          float e = svv[h] + dloc[h];
          e = (e > 0.f) ? e : 0.2f * e;
          w_l[h] = __expf(e - mn[h]);
        }
      } else {
        float e = sArr[s_l] + dloc[0];
        e = (e > 0.f) ? e : 0.2f * e;
        w_l[0] = __expf(e - mn[0]);
      }
    }
    for (int i = 0; i < cn; ++i) {
      int s = __shfl(s_l, i);
      float wh[HH];
#pragma unroll
      for (int h = 0; h < HH; ++h) {
        wh[h] = __shfl(w_l[h], i);
        denom[h] += wh[h];
      }
      float w = wh[lanehead];
      gvec v = *(const gvec*)(hin + (size_t)s * CT + lane * VEC);
#pragma unroll
      for (int k = 0; k < VEC; ++k) acc[k] += w * (float)v[k];
    }
  }

  float dn = denom[lanehead] + 1e-16f;
  struct alignas(sizeof(OutT) * VEC) OutV { OutT v[VEC]; } ov;
#pragma unroll
  for (int k = 0; k < VEC; ++k) {
    float v = acc[k] / dn + bias[lane * VEC + k];
    if (DOELU) v = (v > 0.f) ? v : expm1f(v);
    ov.v[k] = (OutT)v;
  }
  *(OutV*)(outp + (size_t)n * CT + lane * VEC) = ov;
}

// ---------------------------------------------------------------------------
// Allocation head (Wh1 staged in LDS, persistent blocks)
// ---------------------------------------------------------------------------
__global__ __launch_bounds__(256) void k_head(
    const float* __restrict__ emb, const float* __restrict__ Wh1,
    const float* __restrict__ bh1, const float* __restrict__ Wh2,
    const float* __restrict__ bh2, float* __restrict__ scores, int N) {
  __shared__ float w1s[64 * 132];
  __shared__ float w2s[64];
  __shared__ float b1s[64];
  int t = threadIdx.x;
  for (int i = t; i < 64 * 32; i += 256) {
    int r = i >> 5, c4 = i & 31;
    float4 v = ((const float4*)Wh1)[i];
    *(float4*)&w1s[r * 132 + c4 * 4] = v;
  }
  if (t < 64) { w2s[t] = Wh2[t]; b1s[t] = bh1[t]; }
  __syncthreads();
  float b2v = bh2[0];
  int wave = t >> 6, lane = t & 63;
  int gw = blockIdx.x * 4 + wave;
  int nw = gridDim.x * 4;
  for (int n = gw; n < N; n += nw) {
    float2 xv = ((const float2*)(emb + (size_t)n * 128))[lane];
    float z = b1s[lane];
#pragma unroll
    for (int j = 0; j < 32; ++j) {
      float4 w = *(const float4*)&w1s[lane * 132 + 4 * j];
      float a0 = __shfl(xv.x, 2 * j);
      float a1 = __shfl(xv.y, 2 * j);
      float a2 = __shfl(xv.x, 2 * j + 1);
      float a3 = __shfl(xv.y, 2 * j + 1);
      z += w.x * a0 + w.y * a1 + w.z * a2 + w.w * a3;
    }
    z = fmaxf(z, 0.f);
    float v = z * w2s[lane];
#pragma unroll
    for (int off = 32; off; off >>= 1) v += __shfl_down(v, off);
    if (lane == 0) scores[n] = 1.f / (1.f + __expf(-(v + b2v)));
  }
}

// ---------------------------------------------------------------------------

extern "C" void kernel_launch(void* const* d_in, const int* in_sizes, int n_in,
                              void* d_out, int out_size, void* d_ws, size_t ws_size,
                              hipStream_t stream) {
  const float* x   = (const float*)d_in[0];
  const int*   ei  = (const int*)d_in[1];
  const float* W1  = (const float*)d_in[2];
  const float* as1 = (const float*)d_in[3];
  const float* ad1 = (const float*)d_in[4];
  const float* b1  = (const float*)d_in[5];
  const float* W2  = (const float*)d_in[6];
  const float* as2 = (const float*)d_in[7];
  const float* ad2 = (const float*)d_in[8];
  const float* b2  = (const float*)d_in[9];
  const float* W3  = (const float*)d_in[10];
  const float* as3 = (const float*)d_in[11];
  const float* ad3 = (const float*)d_in[12];
  const float* b3  = (const float*)d_in[13];
  const float* Wh1 = (const float*)d_in[14];
  const float* bh1 = (const float*)d_in[15];
  const float* Wh2 = (const float*)d_in[16];
  const float* bh2 = (const float*)d_in[17];
  float* out = (float*)d_out;

  const int F = 256, HC = 512, H = 4, C = 128;
  const int N = in_sizes[0] / F;
  const int E = in_sizes[1] / 2;
  const int Et = E + N;
  const int* srcArr = ei;
  const int* dstArr = ei + E;

  char* ws = (char*)d_ws;
  size_t off = 0;
  auto alloc = [&](size_t bytes) -> void* {
    void* p = ws + off;
    off += (bytes + 255) & ~(size_t)255;
    return p;
  };
  f16*   h16    = (f16*)alloc((size_t)N * HC * 2);
  f16*   hAgg   = (f16*)alloc((size_t)N * HC * 2);
  f16*   W1h    = (f16*)alloc((size_t)HC * F * 2);
  f16*   W2h    = (f16*)alloc((size_t)HC * HC * 2);
  f16*   W3h    = (f16*)alloc((size_t)C * HC * 2);
  int* row_ptr  = (int*)alloc((size_t)(N + 1) * 4);
  // zero region: cnt (N ints) + 3x4 gmax uints + barrier counter, one memset
  char* zr      = (char*)alloc((size_t)N * 4 + 64);
  int* cnt      = (int*)zr;
  unsigned* gm1 = (unsigned*)(zr + (size_t)N * 4);
  unsigned* gm2 = gm1 + 4;
  unsigned* gm3 = gm1 + 8;
  int* arrive   = (int*)(gm1 + 12);
  int* cursor   = (int*)alloc((size_t)N * 4);
  int* perm     = (int*)alloc((size_t)Et * 4);
  float* sArr   = (float*)alloc((size_t)N * H * 4);
  float* dArr   = (float*)alloc((size_t)N * H * 4);
  int* bsum     = (int*)alloc((size_t)260 * 4);
  (void)ws_size; (void)n_in; (void)out_size;

  // ---- CSR build (single fused persistent kernel) ----
  hipMemsetAsync(zr, 0, (size_t)N * 4 + 64, stream);
  int nch = (N + 1023) / 1024;   // 49 <= 256
  k_csr<<<256, 256, 0, stream>>>(dstArr, cnt, row_ptr, cursor, perm, bsum,
                                 arrive, N, E, Et, nch);

  // ---- fp16 weight conversions (one small launch; x converted in hgemm1) ----
  int c1 = HC * F / 4, c2 = HC * HC / 4, c3 = C * HC / 4;
  int ctot = c1 + c2 + c3;
  k_f2h3<<<(ctot + 255) / 256, 256, 0, stream>>>(W1, W1h, c1, W2, W2h, c2,
                                                 W3, W3h, c3);

  int aggGrid = (N + 3) / 4;
  dim3 g1(HC / 128, (N + 127) / 128);
  dim3 g3(C / 128, (N + 127) / 128);

  // ---- layer 1: F -> H*C, elu (A = x in fp32, converted during staging) ----
  k_hgemm_nt<true><<<g1, 256, 0, stream>>>(x, W1h, h16, N, HC, F,
                                           as1, ad1, sArr, dArr, gm1, H);
  k_aggregate<4, 512, true, f16><<<aggGrid, 256, 0, stream>>>(
      h16, sArr, dArr, row_ptr, perm, srcArr, gm1, b1, hAgg, N, E);

  // ---- layer 2: H*C -> H*C, elu ----
  k_hgemm_nt<false><<<g1, 256, 0, stream>>>(hAgg, W2h, h16, N, HC, HC,
                                            as2, ad2, sArr, dArr, gm2, H);
  k_aggregate<4, 512, true, f16><<<aggGrid, 256, 0, stream>>>(
      h16, sArr, dArr, row_ptr, perm, srcArr, gm2, b2, hAgg, N, E);

  // ---- layer 3: H*C -> C, single head, no concat/elu -> embeddings ----
  k_hgemm_nt<false><<<g3, 256, 0, stream>>>(hAgg, W3h, h16, N, C, HC,
                                            as3, ad3, sArr, dArr, gm3, 1);
  k_aggregate<1, 128, false, float><<<aggGrid, 256, 0, stream>>>(
      h16, sArr, dArr, row_ptr, perm, srcArr, gm3, b3, out, N, E);

  // ---- allocation head ----
  k_head<<<512, 256, 0, stream>>>(out, Wh1, bh1, Wh2, bh2, out + (size_t)N * C, N);
}